// Round 5
// baseline (341.345 us; speedup 1.0000x reference)
//
#include <hip/hip_runtime.h>
#include <math.h>

#define N_NODES 102400
#define N_EDGES 1638400
#define G_GRAPHS 256
#define NODES_PER_G 400
#define CAPB 7168          // per-graph edge bucket capacity (mean 6400, +9.6 sigma)
#define F_IN  64
#define H1    4
#define C1    32
#define F_MID 128
#define C2    32
#define CLIN  5
#define NEG   0.2f

__device__ __forceinline__ float lrelu(float x) { return x > 0.f ? x : NEG * x; }
__device__ __forceinline__ float elu(float x)   { return x > 0.f ? x : expm1f(x); }

// round-to-nearest-even fp32 -> bf16 (as ushort)
__device__ __forceinline__ unsigned short f2bf(float f) {
    unsigned u = __float_as_uint(f);
    u = (u + 0x7fffu + ((u >> 16) & 1u)) >> 16;
    return (unsigned short)u;
}
__device__ __forceinline__ float bfLO(unsigned p) { return __uint_as_float(p << 16); }
__device__ __forceinline__ float bfHI(unsigned p) { return __uint_as_float(p & 0xffff0000u); }

// ---------------- CSR build, LDS-binned (no global random atomics) ----------------
__global__ __launch_bounds__(256) void bin_k(const int* __restrict__ ei,
                                             int* __restrict__ gcnt,
                                             unsigned* __restrict__ binned) {
    __shared__ int hist[256];
    __shared__ int off[256];
    int t = threadIdx.x;
    hist[t] = 0;
    __syncthreads();
    int i0 = blockIdx.x * 4096;
#pragma unroll
    for (int j = 0; j < 16; ++j) {
        int d = ei[N_EDGES + i0 + j * 256 + t];
        atomicAdd(&hist[d / NODES_PER_G], 1);
    }
    __syncthreads();
    off[t] = atomicAdd(&gcnt[t], hist[t]);
    hist[t] = 0;                         // reuse as per-bucket running slot
    __syncthreads();
#pragma unroll
    for (int j = 0; j < 16; ++j) {
        int idx = i0 + j * 256 + t;
        int s = ei[idx];
        int d = ei[N_EDGES + idx];
        int g = d / NODES_PER_G;
        int dl = d - g * NODES_PER_G;
        int slot = atomicAdd(&hist[g], 1);
        binned[(size_t)g * CAPB + off[g] + slot] = (unsigned)s | ((unsigned)dl << 17);
    }
}

__global__ __launch_bounds__(512) void build_k(
    const int* __restrict__ gcnt, unsigned* __restrict__ binned,
    int* __restrict__ row_ptr, int* __restrict__ row_end)
{
    __shared__ unsigned edg[CAPB];
    __shared__ int coll[CAPB];
    __shared__ int hist[512];
    __shared__ int cur[NODES_PER_G];
    int g = blockIdx.x, t = threadIdx.x;
    int ne = gcnt[g];
    size_t base = (size_t)g * CAPB;
    for (int i = t; i < ne; i += 512) edg[i] = binned[base + i];
    hist[t] = 0;
    __syncthreads();
    for (int i = t; i < ne; i += 512) atomicAdd(&hist[edg[i] >> 17], 1);
    __syncthreads();
    int v = hist[t];
    for (int off = 1; off < 512; off <<= 1) {
        int tmp = (t >= off) ? hist[t - off] : 0;
        __syncthreads();
        hist[t] += tmp;
        __syncthreads();
    }
    int excl = hist[t] - v;
    if (t < NODES_PER_G) {
        cur[t] = excl;
        row_ptr[g * NODES_PER_G + t] = (int)base + excl;
    }
    __syncthreads();
    for (int i = t; i < ne; i += 512) {
        unsigned e = edg[i];
        int pos = atomicAdd(&cur[e >> 17], 1);
        coll[pos] = (int)(e & 0x1FFFFu);
    }
    __syncthreads();
    if (t < NODES_PER_G) row_end[g * NODES_PER_G + t] = (int)base + cur[t];
    for (int i = t; i < ne; i += 512) binned[base + i] = (unsigned)coll[i];
}

// ---- ht_k: h~ = x @ W1 (fp32 accum) -> bf16 table hth [N][128]
//            + layer-1 logits split: als1[n][4] (src), ald1[n][4] (dst)
__global__ __launch_bounds__(256) void ht_k(
    const float* __restrict__ x, const float* __restrict__ W1,
    const float* __restrict__ a_src1, const float* __restrict__ a_dst1,
    unsigned short* __restrict__ hth, float* __restrict__ als1, float* __restrict__ ald1)
{
    __shared__ float xs[32][65];
    __shared__ float W1s[64 * 160];
    int t = threadIdx.x;
    int n0 = blockIdx.x * 32;
#pragma unroll
    for (int j = 0; j < 8; ++j) {
        int idx = t + 256 * j;
        xs[idx >> 6][idx & 63] = x[(size_t)n0 * F_IN + idx];
    }
#pragma unroll
    for (int j = 0; j < 8; ++j) {
        int q = t + 256 * j;              // float4 id, 2048 total (64x128 floats)
        int k = q >> 5, c0 = (q & 31) * 4;
        float4 v = ((const float4*)W1)[q];
        *(float4*)&W1s[k * 160 + (c0 >> 4) * 20 + (c0 & 15)] = v;
    }
    __syncthreads();
    int n = t >> 3, cg = t & 7;
    float acc[16];
#pragma unroll
    for (int j = 0; j < 16; ++j) acc[j] = 0.f;
    const float* wp = &W1s[cg * 20];
#pragma unroll 4
    for (int k = 0; k < F_IN; ++k) {
        float a = xs[n][k];
        const float* wr = wp + k * 160;
#pragma unroll
        for (int j = 0; j < 4; ++j) {
            float4 w = *(const float4*)(wr + 4 * j);
            acc[4 * j + 0] += a * w.x;
            acc[4 * j + 1] += a * w.y;
            acc[4 * j + 2] += a * w.z;
            acc[4 * j + 3] += a * w.w;
        }
    }
    int head = cg >> 1, hoff = (cg & 1) * 16;
    const float* asp = a_src1 + head * 32 + hoff;
    const float* adp = a_dst1 + head * 32 + hoff;
    float ps = 0.f, pd = 0.f;
#pragma unroll
    for (int j = 0; j < 16; ++j) { ps += acc[j] * asp[j]; pd += acc[j] * adp[j]; }
    ps += __shfl_xor(ps, 1);
    pd += __shfl_xor(pd, 1);
    if ((cg & 1) == 0) {
        als1[(size_t)(n0 + n) * 4 + head] = ps;
        ald1[(size_t)(n0 + n) * 4 + head] = pd;
    }
    unsigned u[8];
#pragma unroll
    for (int j = 0; j < 8; ++j)
        u[j] = ((unsigned)f2bf(acc[2 * j + 1]) << 16) | (unsigned)f2bf(acc[2 * j]);
    uint4* hp = (uint4*)(hth + ((size_t)(n0 + n) * F_MID + cg * 16));
    hp[0] = make_uint4(u[0], u[1], u[2], u[3]);
    hp[1] = make_uint4(u[4], u[5], u[6], u[7]);
}

// ---- agg1_k: barrier-free, zero-LDS layer-1 aggregation (one wave per dst).
// Scalarized edge loop + masked 8-wide tail. Writes h1 fp32 [N][128].
__global__ __launch_bounds__(256, 8) void agg1_k(
    const int* __restrict__ row_ptr, const int* __restrict__ row_end,
    const unsigned* __restrict__ col, const unsigned short* __restrict__ hth,
    const float* __restrict__ als1, const float* __restrict__ ald1,
    const float* __restrict__ b1, float* __restrict__ h1)
{
    int t = threadIdx.x;
    int wv = t >> 6, lane = t & 63, h = lane >> 4;
    int d = blockIdx.x * 4 + wv;
    const unsigned* hv = (const unsigned*)hth;    // [N][64] packed bf16 pairs

    float adv = ald1[d * 4 + h];
    float w = __expf(lrelu(als1[d * 4 + h] + adv));     // self loop
    unsigned p = hv[(size_t)d * 64 + lane];
    float a0 = w * bfLO(p), a1 = w * bfHI(p);
    float den = w;

    int e0 = __builtin_amdgcn_readfirstlane(row_ptr[d]);
    int e1 = __builtin_amdgcn_readfirstlane(row_end[d]);
    int e = e0;
    for (; e + 8 <= e1; e += 8) {
        int s0 = __builtin_amdgcn_readfirstlane((int)col[e]);
        int s1 = __builtin_amdgcn_readfirstlane((int)col[e + 1]);
        int s2 = __builtin_amdgcn_readfirstlane((int)col[e + 2]);
        int s3 = __builtin_amdgcn_readfirstlane((int)col[e + 3]);
        int s4 = __builtin_amdgcn_readfirstlane((int)col[e + 4]);
        int s5 = __builtin_amdgcn_readfirstlane((int)col[e + 5]);
        int s6 = __builtin_amdgcn_readfirstlane((int)col[e + 6]);
        int s7 = __builtin_amdgcn_readfirstlane((int)col[e + 7]);
        unsigned p0 = hv[(size_t)s0 * 64 + lane];
        unsigned p1 = hv[(size_t)s1 * 64 + lane];
        unsigned p2 = hv[(size_t)s2 * 64 + lane];
        unsigned p3 = hv[(size_t)s3 * 64 + lane];
        unsigned p4 = hv[(size_t)s4 * 64 + lane];
        unsigned p5 = hv[(size_t)s5 * 64 + lane];
        unsigned p6 = hv[(size_t)s6 * 64 + lane];
        unsigned p7 = hv[(size_t)s7 * 64 + lane];
        float v0 = als1[s0 * 4 + h];
        float v1 = als1[s1 * 4 + h];
        float v2 = als1[s2 * 4 + h];
        float v3 = als1[s3 * 4 + h];
        float v4 = als1[s4 * 4 + h];
        float v5 = als1[s5 * 4 + h];
        float v6 = als1[s6 * 4 + h];
        float v7 = als1[s7 * 4 + h];
        float w0 = __expf(lrelu(v0 + adv));
        float w1 = __expf(lrelu(v1 + adv));
        float w2 = __expf(lrelu(v2 + adv));
        float w3 = __expf(lrelu(v3 + adv));
        float w4 = __expf(lrelu(v4 + adv));
        float w5 = __expf(lrelu(v5 + adv));
        float w6 = __expf(lrelu(v6 + adv));
        float w7 = __expf(lrelu(v7 + adv));
        a0 += w0 * bfLO(p0) + w1 * bfLO(p1) + w2 * bfLO(p2) + w3 * bfLO(p3);
        a0 += w4 * bfLO(p4) + w5 * bfLO(p5) + w6 * bfLO(p6) + w7 * bfLO(p7);
        a1 += w0 * bfHI(p0) + w1 * bfHI(p1) + w2 * bfHI(p2) + w3 * bfHI(p3);
        a1 += w4 * bfHI(p4) + w5 * bfHI(p5) + w6 * bfHI(p6) + w7 * bfHI(p7);
        den += w0 + w1 + w2 + w3 + w4 + w5 + w6 + w7;
    }
    if (e < e1) {   // masked 8-wide tail: one latency round instead of up to 7
        int last = e1 - 1;
        int i1 = (e + 1 < e1) ? e + 1 : last;
        int i2 = (e + 2 < e1) ? e + 2 : last;
        int i3 = (e + 3 < e1) ? e + 3 : last;
        int i4 = (e + 4 < e1) ? e + 4 : last;
        int i5 = (e + 5 < e1) ? e + 5 : last;
        int i6 = (e + 6 < e1) ? e + 6 : last;
        int i7 = (e + 7 < e1) ? e + 7 : last;
        int s0 = __builtin_amdgcn_readfirstlane((int)col[e]);
        int s1 = __builtin_amdgcn_readfirstlane((int)col[i1]);
        int s2 = __builtin_amdgcn_readfirstlane((int)col[i2]);
        int s3 = __builtin_amdgcn_readfirstlane((int)col[i3]);
        int s4 = __builtin_amdgcn_readfirstlane((int)col[i4]);
        int s5 = __builtin_amdgcn_readfirstlane((int)col[i5]);
        int s6 = __builtin_amdgcn_readfirstlane((int)col[i6]);
        int s7 = __builtin_amdgcn_readfirstlane((int)col[i7]);
        unsigned p0 = hv[(size_t)s0 * 64 + lane];
        unsigned p1 = hv[(size_t)s1 * 64 + lane];
        unsigned p2 = hv[(size_t)s2 * 64 + lane];
        unsigned p3 = hv[(size_t)s3 * 64 + lane];
        unsigned p4 = hv[(size_t)s4 * 64 + lane];
        unsigned p5 = hv[(size_t)s5 * 64 + lane];
        unsigned p6 = hv[(size_t)s6 * 64 + lane];
        unsigned p7 = hv[(size_t)s7 * 64 + lane];
        float w0 = __expf(lrelu(als1[s0 * 4 + h] + adv));
        float w1 = (e + 1 < e1) ? __expf(lrelu(als1[s1 * 4 + h] + adv)) : 0.f;
        float w2 = (e + 2 < e1) ? __expf(lrelu(als1[s2 * 4 + h] + adv)) : 0.f;
        float w3 = (e + 3 < e1) ? __expf(lrelu(als1[s3 * 4 + h] + adv)) : 0.f;
        float w4 = (e + 4 < e1) ? __expf(lrelu(als1[s4 * 4 + h] + adv)) : 0.f;
        float w5 = (e + 5 < e1) ? __expf(lrelu(als1[s5 * 4 + h] + adv)) : 0.f;
        float w6 = (e + 6 < e1) ? __expf(lrelu(als1[s6 * 4 + h] + adv)) : 0.f;
        float w7 = (e + 7 < e1) ? __expf(lrelu(als1[s7 * 4 + h] + adv)) : 0.f;
        a0 += w0 * bfLO(p0) + w1 * bfLO(p1) + w2 * bfLO(p2) + w3 * bfLO(p3);
        a0 += w4 * bfLO(p4) + w5 * bfLO(p5) + w6 * bfLO(p6) + w7 * bfLO(p7);
        a1 += w0 * bfHI(p0) + w1 * bfHI(p1) + w2 * bfHI(p2) + w3 * bfHI(p3);
        a1 += w4 * bfHI(p4) + w5 * bfHI(p5) + w6 * bfHI(p6) + w7 * bfHI(p7);
        den += w0 + w1 + w2 + w3 + w4 + w5 + w6 + w7;
    }
    float inv = 1.f / den;
    float2 bb = ((const float2*)b1)[lane];
    float2 o;
    o.x = elu(a0 * inv + bb.x);
    o.y = elu(a1 * inv + bb.y);
    ((float2*)h1)[(size_t)d * 64 + lane] = o;
}

// ---- dense2_k: h2 = h1 @ W2 (bf16 store) + layer-2 logits ----
__global__ __launch_bounds__(256) void dense2_k(
    const float* __restrict__ h1, const float* __restrict__ W2,
    const float* __restrict__ a_src2, const float* __restrict__ a_dst2,
    unsigned short* __restrict__ h2h, float* __restrict__ al_s2, float* __restrict__ al_d2)
{
    __shared__ float hs[32 * 132];    // rows stride 132 (==4 mod 32 -> 8 banks, bcast)
    __shared__ float W2s[128 * 32];   // flat: o-quads cover all 32 banks once
    __shared__ float h2s[32 * 36];
    int t = threadIdx.x;
    int n0 = blockIdx.x * 32;
#pragma unroll
    for (int j = 0; j < 4; ++j) {
        int q = t + 256 * j;                 // float4 id over 32x128
        int n = q >> 5, c0 = (q & 31) * 4;
        *(float4*)&hs[n * 132 + c0] = ((const float4*)h1)[(size_t)n0 * 32 + q];
        ((float4*)W2s)[q] = ((const float4*)W2)[q];
    }
    __syncthreads();
    int n = t >> 3, o4 = (t & 7) * 4;
    float4 acc = make_float4(0.f, 0.f, 0.f, 0.f);
#pragma unroll 8
    for (int k = 0; k < F_MID; ++k) {
        float a = hs[n * 132 + k];
        float4 w = *(const float4*)&W2s[k * 32 + o4];
        acc.x += a * w.x; acc.y += a * w.y; acc.z += a * w.z; acc.w += a * w.w;
    }
    unsigned lo = ((unsigned)f2bf(acc.y) << 16) | (unsigned)f2bf(acc.x);
    unsigned hi = ((unsigned)f2bf(acc.w) << 16) | (unsigned)f2bf(acc.z);
    ((uint2*)h2h)[(((size_t)(n0 + n)) * C2 + o4) >> 2] = make_uint2(lo, hi);
    *(float4*)&h2s[n * 36 + o4] = acc;
    __syncthreads();
    if (t < 64) {
        int which = t >> 5, nn = t & 31;
        const float* a = which ? a_dst2 : a_src2;
        float s = 0.f;
#pragma unroll
        for (int k = 0; k < C2; ++k) s += h2s[nn * 36 + k] * a[k];
        if (which) al_d2[n0 + nn] = s;
        else       al_s2[n0 + nn] = s;
    }
}

// ---- gather2: one WAVE per dst. lane = (quartet q, channel-pair cp).
// 4 edges per instruction (4 x 16-lane 64B rows), 8 edges in flight, masked
// tail, quartet shfl-reduce, per-block (4 dsts, same graph) LDS pool + one
// 32-lane atomic per block.
__global__ __launch_bounds__(256, 8) void gather2(
    const int* __restrict__ row_ptr, const int* __restrict__ row_end,
    const unsigned* __restrict__ col, const float* __restrict__ al_src,
    const float* __restrict__ al_dst, const unsigned short* __restrict__ h2h,
    const float* __restrict__ b2, const int* __restrict__ batch,
    float* __restrict__ pooled)
{
    __shared__ float sm[4][C2];
    int t = threadIdx.x;
    int wv = t >> 6, lane = t & 63;
    int q = lane >> 4, cp = lane & 15;
    int d = blockIdx.x * 4 + wv;
    const unsigned* hv = (const unsigned*)h2h;   // [N][16] packed bf16 pairs

    float ad = al_dst[d];
    float a0 = 0.f, a1 = 0.f, den = 0.f;
    if (q == 0) {                                 // self loop (once)
        float ws = __expf(lrelu(al_src[d] + ad));
        unsigned p = hv[(size_t)d * 16 + cp];
        a0 = ws * bfLO(p); a1 = ws * bfHI(p); den = ws;
    }
    int e0 = __builtin_amdgcn_readfirstlane(row_ptr[d]);
    int e1 = __builtin_amdgcn_readfirstlane(row_end[d]);
    int e = e0;
    for (; e + 8 <= e1; e += 8) {
        int sa = (int)col[e + q];                 // 16 lanes same addr
        int sb = (int)col[e + 4 + q];
        unsigned pa = hv[(size_t)sa * 16 + cp];
        unsigned pb = hv[(size_t)sb * 16 + cp];
        float wa = __expf(lrelu(al_src[sa] + ad));
        float wb = __expf(lrelu(al_src[sb] + ad));
        a0 += wa * bfLO(pa) + wb * bfLO(pb);
        a1 += wa * bfHI(pa) + wb * bfHI(pb);
        den += wa + wb;
    }
    if (e < e1) {                                 // masked 8-wide tail
        int last = e1 - 1;
        int ia = e + q;     bool ma = ia < e1; ia = ma ? ia : last;
        int ib = e + 4 + q; bool mb = ib < e1; ib = mb ? ib : last;
        int sa = (int)col[ia];
        int sb = (int)col[ib];
        unsigned pa = hv[(size_t)sa * 16 + cp];
        unsigned pb = hv[(size_t)sb * 16 + cp];
        float wa = ma ? __expf(lrelu(al_src[sa] + ad)) : 0.f;
        float wb = mb ? __expf(lrelu(al_src[sb] + ad)) : 0.f;
        a0 += wa * bfLO(pa) + wb * bfLO(pb);
        a1 += wa * bfHI(pa) + wb * bfHI(pb);
        den += wa + wb;
    }
    // reduce across quartets
    a0 += __shfl_xor(a0, 16);  a0 += __shfl_xor(a0, 32);
    a1 += __shfl_xor(a1, 16);  a1 += __shfl_xor(a1, 32);
    den += __shfl_xor(den, 16); den += __shfl_xor(den, 32);
    if (q == 0) {
        float inv = 1.f / den;
        float2 bb = ((const float2*)b2)[cp];
        sm[wv][2 * cp]     = elu(a0 * inv + bb.x);
        sm[wv][2 * cp + 1] = elu(a1 * inv + bb.y);
    }
    __syncthreads();
    if (t < C2) {   // 400 % 4 == 0 -> all 4 dsts of a block share one graph
        float s = sm[0][t] + sm[1][t] + sm[2][t] + sm[3][t];
        int g = batch[blockIdx.x * 4];
        atomicAdd(&pooled[g * C2 + t], s);
    }
}

// ---- classifier head: one thread per graph (400 nodes/graph exactly) ----
__global__ __launch_bounds__(256) void head_k(
    const float* __restrict__ pooled, const float* __restrict__ clinical,
    const float* __restrict__ Wc1, const float* __restrict__ bc1,
    const float* __restrict__ Wc2, const float* __restrict__ bc2,
    float* __restrict__ out)
{
    int g = threadIdx.x;
    float fused[C2 + CLIN];
    const float inv = 1.f / 400.f;
#pragma unroll
    for (int c = 0; c < C2; ++c) fused[c] = pooled[g * C2 + c] * inv;
#pragma unroll
    for (int c = 0; c < CLIN; ++c) fused[C2 + c] = clinical[g * CLIN + c];
    float o = bc2[0];
#pragma unroll
    for (int j = 0; j < 16; ++j) {
        float acc = bc1[j];
#pragma unroll
        for (int k = 0; k < C2 + CLIN; ++k) acc += fused[k] * Wc1[k * 16 + j];
        o += (acc > 0.f ? acc : expm1f(acc)) * Wc2[j];
    }
    out[g] = o;
}

extern "C" void kernel_launch(void* const* d_in, const int* in_sizes, int n_in,
                              void* d_out, int out_size, void* d_ws, size_t ws_size,
                              hipStream_t stream) {
    const float* x        = (const float*)d_in[0];
    const int*   ei       = (const int*)  d_in[1];
    const int*   batch    = (const int*)  d_in[2];
    const float* clinical = (const float*)d_in[3];
    const float* W1       = (const float*)d_in[4];
    const float* a_src1   = (const float*)d_in[5];
    const float* a_dst1   = (const float*)d_in[6];
    const float* b1       = (const float*)d_in[7];
    const float* W2       = (const float*)d_in[8];
    const float* a_src2   = (const float*)d_in[9];
    const float* a_dst2   = (const float*)d_in[10];
    const float* b2       = (const float*)d_in[11];
    const float* Wc1      = (const float*)d_in[12];
    const float* bc1      = (const float*)d_in[13];
    const float* Wc2      = (const float*)d_in[14];
    const float* bc2      = (const float*)d_in[15];
    float* out = (float*)d_out;

    const size_t N = N_NODES;
    float* ws = (float*)d_ws;
    size_t off = 0;
    float* als1   = ws + off; off += N * 4;
    float* ald1   = ws + off; off += N * 4;
    float* al_s2  = ws + off; off += N;
    float* al_d2  = ws + off; off += N;
    float* pooled = ws + off; off += (size_t)G_GRAPHS * C2;
    unsigned short* hth = (unsigned short*)(ws + off); off += N * F_MID / 2;  // bf16 h~
    float* h1     = ws + off; off += N * F_MID;                               // fp32 h1
    unsigned short* h2h = (unsigned short*)(ws + off); off += N * C2 / 2;     // bf16 h2
    int* row_ptr = (int*)(ws + off); off += N;
    int* row_end = (int*)(ws + off); off += N;
    int* gcnt    = (int*)(ws + off); off += 256;
    unsigned* binned = (unsigned*)(ws + off); off += (size_t)G_GRAPHS * CAPB; // also final col

    hipMemsetAsync(gcnt, 0, 256 * sizeof(int), stream);
    hipMemsetAsync(pooled, 0, G_GRAPHS * C2 * sizeof(float), stream);

    // CSR build: LDS binning
    bin_k  <<<N_EDGES / 4096, 256, 0, stream>>>(ei, gcnt, binned);
    build_k<<<G_GRAPHS, 512, 0, stream>>>(gcnt, binned, row_ptr, row_end);

    // h~ = x@W1 (bf16 table) + layer-1 logits (split src/dst)
    ht_k<<<N_NODES / 32, 256, 0, stream>>>(x, W1, a_src1, a_dst1, hth, als1, ald1);

    // barrier-free layer-1 aggregation -> h1 fp32
    agg1_k<<<N_NODES / 4, 256, 0, stream>>>(row_ptr, row_end, binned, hth, als1, ald1,
                                            b1, h1);

    // h2 = h1@W2 (bf16) + layer-2 logits
    dense2_k<<<N_NODES / 32, 256, 0, stream>>>(h1, W2, a_src2, a_dst2, h2h, al_s2, al_d2);

    // layer 2 gather (wave-per-dst) + fused pooling
    gather2<<<N_NODES / 4, 256, 0, stream>>>(row_ptr, row_end, binned, al_s2, al_d2, h2h,
                                             b2, batch, pooled);

    // head
    head_k<<<1, G_GRAPHS, 0, stream>>>(pooled, clinical, Wc1, bc1, Wc2, bc2, out);
}

// Round 6
// 309.996 us; speedup vs baseline: 1.1011x; 1.1011x over previous
//
#include <hip/hip_runtime.h>
#include <math.h>

#define N_NODES 102400
#define N_EDGES 1638400
#define G_GRAPHS 256
#define NODES_PER_G 400
#define CAPB 7168          // per-graph edge bucket capacity (mean 6400, +9.6 sigma)
#define F_IN  64
#define H1    4
#define C1    32
#define F_MID 128
#define C2    32
#define CLIN  5
#define NEG   0.2f

__device__ __forceinline__ float lrelu(float x) { return x > 0.f ? x : NEG * x; }
__device__ __forceinline__ float elu(float x)   { return x > 0.f ? x : expm1f(x); }

// round-to-nearest-even fp32 -> bf16 (as ushort)
__device__ __forceinline__ unsigned short f2bf(float f) {
    unsigned u = __float_as_uint(f);
    u = (u + 0x7fffu + ((u >> 16) & 1u)) >> 16;
    return (unsigned short)u;
}
__device__ __forceinline__ float bfLO(unsigned p) { return __uint_as_float(p << 16); }
__device__ __forceinline__ float bfHI(unsigned p) { return __uint_as_float(p & 0xffff0000u); }
// unpack 4 bf16 (uint2) -> float4
__device__ __forceinline__ float4 bf2f4(uint2 p) {
    return make_float4(__uint_as_float(p.x << 16), __uint_as_float(p.x & 0xffff0000u),
                       __uint_as_float(p.y << 16), __uint_as_float(p.y & 0xffff0000u));
}

// ---------------- CSR build, LDS-binned (no global random atomics) ----------------
__global__ __launch_bounds__(256) void bin_k(const int* __restrict__ ei,
                                             int* __restrict__ gcnt,
                                             unsigned* __restrict__ binned) {
    __shared__ int hist[256];
    __shared__ int off[256];
    int t = threadIdx.x;
    hist[t] = 0;
    __syncthreads();
    int i0 = blockIdx.x * 4096;
#pragma unroll
    for (int j = 0; j < 16; ++j) {
        int d = ei[N_EDGES + i0 + j * 256 + t];
        atomicAdd(&hist[d / NODES_PER_G], 1);
    }
    __syncthreads();
    off[t] = atomicAdd(&gcnt[t], hist[t]);
    hist[t] = 0;                         // reuse as per-bucket running slot
    __syncthreads();
#pragma unroll
    for (int j = 0; j < 16; ++j) {
        int idx = i0 + j * 256 + t;
        int s = ei[idx];
        int d = ei[N_EDGES + idx];
        int g = d / NODES_PER_G;
        int dl = d - g * NODES_PER_G;
        int slot = atomicAdd(&hist[g], 1);
        binned[(size_t)g * CAPB + off[g] + slot] = (unsigned)s | ((unsigned)dl << 17);
    }
}

__global__ __launch_bounds__(512) void build_k(
    const int* __restrict__ gcnt, unsigned* __restrict__ binned,
    int* __restrict__ row_ptr, int* __restrict__ row_end)
{
    __shared__ unsigned edg[CAPB];
    __shared__ int coll[CAPB];
    __shared__ int hist[512];
    __shared__ int cur[NODES_PER_G];
    int g = blockIdx.x, t = threadIdx.x;
    int ne = gcnt[g];
    size_t base = (size_t)g * CAPB;
    for (int i = t; i < ne; i += 512) edg[i] = binned[base + i];
    hist[t] = 0;
    __syncthreads();
    for (int i = t; i < ne; i += 512) atomicAdd(&hist[edg[i] >> 17], 1);
    __syncthreads();
    int v = hist[t];
    for (int off = 1; off < 512; off <<= 1) {
        int tmp = (t >= off) ? hist[t - off] : 0;
        __syncthreads();
        hist[t] += tmp;
        __syncthreads();
    }
    int excl = hist[t] - v;
    if (t < NODES_PER_G) {
        cur[t] = excl;
        row_ptr[g * NODES_PER_G + t] = (int)base + excl;
    }
    __syncthreads();
    for (int i = t; i < ne; i += 512) {
        unsigned e = edg[i];
        int pos = atomicAdd(&cur[e >> 17], 1);
        coll[pos] = (int)(e & 0x1FFFFu);
    }
    __syncthreads();
    if (t < NODES_PER_G) row_end[g * NODES_PER_G + t] = (int)base + cur[t];
    for (int i = t; i < ne; i += 512) binned[base + i] = (unsigned)coll[i];
}

// ---- ht_k: h~ = x @ W1 (fp32 accum) -> bf16 table hth [N][128]
//            + layer-1 logits split: als1[n][4] (src), ald1[n][4] (dst)
__global__ __launch_bounds__(256) void ht_k(
    const float* __restrict__ x, const float* __restrict__ W1,
    const float* __restrict__ a_src1, const float* __restrict__ a_dst1,
    unsigned short* __restrict__ hth, float* __restrict__ als1, float* __restrict__ ald1)
{
    __shared__ float xs[32][65];
    __shared__ float W1s[64 * 160];
    int t = threadIdx.x;
    int n0 = blockIdx.x * 32;
#pragma unroll
    for (int j = 0; j < 8; ++j) {
        int idx = t + 256 * j;
        xs[idx >> 6][idx & 63] = x[(size_t)n0 * F_IN + idx];
    }
#pragma unroll
    for (int j = 0; j < 8; ++j) {
        int q = t + 256 * j;              // float4 id, 2048 total (64x128 floats)
        int k = q >> 5, c0 = (q & 31) * 4;
        float4 v = ((const float4*)W1)[q];
        *(float4*)&W1s[k * 160 + (c0 >> 4) * 20 + (c0 & 15)] = v;
    }
    __syncthreads();
    int n = t >> 3, cg = t & 7;
    float acc[16];
#pragma unroll
    for (int j = 0; j < 16; ++j) acc[j] = 0.f;
    const float* wp = &W1s[cg * 20];
#pragma unroll 4
    for (int k = 0; k < F_IN; ++k) {
        float a = xs[n][k];
        const float* wr = wp + k * 160;
#pragma unroll
        for (int j = 0; j < 4; ++j) {
            float4 w = *(const float4*)(wr + 4 * j);
            acc[4 * j + 0] += a * w.x;
            acc[4 * j + 1] += a * w.y;
            acc[4 * j + 2] += a * w.z;
            acc[4 * j + 3] += a * w.w;
        }
    }
    int head = cg >> 1, hoff = (cg & 1) * 16;
    const float* asp = a_src1 + head * 32 + hoff;
    const float* adp = a_dst1 + head * 32 + hoff;
    float ps = 0.f, pd = 0.f;
#pragma unroll
    for (int j = 0; j < 16; ++j) { ps += acc[j] * asp[j]; pd += acc[j] * adp[j]; }
    ps += __shfl_xor(ps, 1);
    pd += __shfl_xor(pd, 1);
    if ((cg & 1) == 0) {
        als1[(size_t)(n0 + n) * 4 + head] = ps;
        ald1[(size_t)(n0 + n) * 4 + head] = pd;
    }
    unsigned u[8];
#pragma unroll
    for (int j = 0; j < 8; ++j)
        u[j] = ((unsigned)f2bf(acc[2 * j + 1]) << 16) | (unsigned)f2bf(acc[2 * j]);
    uint4* hp = (uint4*)(hth + ((size_t)(n0 + n) * F_MID + cg * 16));
    hp[0] = make_uint4(u[0], u[1], u[2], u[3]);
    hp[1] = make_uint4(u[4], u[5], u[6], u[7]);
}

// ---- agg1_k: barrier-free, zero-LDS layer-1 aggregation (one wave per dst).
// Weights computed ONCE in "weight layout" (lane = edge(0..7) + 8*head) and
// shfl-broadcast to the channel lanes -- removes the 16x redundant exp chains
// and 15 of 16 uniform/als loads per 8-edge group. Bitwise-identical math.
__global__ __launch_bounds__(256, 8) void agg1_k(
    const int* __restrict__ row_ptr, const int* __restrict__ row_end,
    const unsigned* __restrict__ col, const unsigned short* __restrict__ hth,
    const float* __restrict__ als1, const float* __restrict__ ald1,
    const float* __restrict__ b1, float* __restrict__ h1)
{
    int t = threadIdx.x;
    int wv = t >> 6, lane = t & 63, h = lane >> 4;
    int hw = (lane >> 3) & 3;          // weight-layout head (dup in upper half)
    int ew = lane & 7;                 // weight-layout edge slot
    int d = blockIdx.x * 4 + wv;
    const unsigned* hv = (const unsigned*)hth;    // [N][64] packed bf16 pairs

    float adv  = ald1[d * 4 + h];      // channel-layout (self loop)
    float advB = ald1[d * 4 + hw];     // weight-layout (edge loop)
    float w = __expf(lrelu(als1[d * 4 + h] + adv));     // self loop
    unsigned p = hv[(size_t)d * 64 + lane];
    float a0 = w * bfLO(p), a1 = w * bfHI(p);
    float den = w;

    int bidx = (h << 3);               // base shfl index for this channel-lane's head

    int e0 = __builtin_amdgcn_readfirstlane(row_ptr[d]);
    int e1 = __builtin_amdgcn_readfirstlane(row_end[d]);
    int e = e0;
    for (; e + 8 <= e1; e += 8) {
        unsigned sv = col[e + ew];                 // 1 coalesced 32B load
        int s0 = __builtin_amdgcn_readlane(sv, 0);
        int s1 = __builtin_amdgcn_readlane(sv, 1);
        int s2 = __builtin_amdgcn_readlane(sv, 2);
        int s3 = __builtin_amdgcn_readlane(sv, 3);
        int s4 = __builtin_amdgcn_readlane(sv, 4);
        int s5 = __builtin_amdgcn_readlane(sv, 5);
        int s6 = __builtin_amdgcn_readlane(sv, 6);
        int s7 = __builtin_amdgcn_readlane(sv, 7);
        unsigned p0 = hv[(size_t)s0 * 64 + lane];
        unsigned p1 = hv[(size_t)s1 * 64 + lane];
        unsigned p2 = hv[(size_t)s2 * 64 + lane];
        unsigned p3 = hv[(size_t)s3 * 64 + lane];
        unsigned p4 = hv[(size_t)s4 * 64 + lane];
        unsigned p5 = hv[(size_t)s5 * 64 + lane];
        unsigned p6 = hv[(size_t)s6 * 64 + lane];
        unsigned p7 = hv[(size_t)s7 * 64 + lane];
        float avv  = als1[(size_t)sv * 4 + hw];    // 1 gather (weight layout)
        float wAll = __expf(lrelu(avv + advB));    // 1 exp chain
        float w0 = __shfl(wAll, bidx + 0);
        float w1 = __shfl(wAll, bidx + 1);
        float w2 = __shfl(wAll, bidx + 2);
        float w3 = __shfl(wAll, bidx + 3);
        float w4 = __shfl(wAll, bidx + 4);
        float w5 = __shfl(wAll, bidx + 5);
        float w6 = __shfl(wAll, bidx + 6);
        float w7 = __shfl(wAll, bidx + 7);
        a0 += w0 * bfLO(p0) + w1 * bfLO(p1) + w2 * bfLO(p2) + w3 * bfLO(p3);
        a0 += w4 * bfLO(p4) + w5 * bfLO(p5) + w6 * bfLO(p6) + w7 * bfLO(p7);
        a1 += w0 * bfHI(p0) + w1 * bfHI(p1) + w2 * bfHI(p2) + w3 * bfHI(p3);
        a1 += w4 * bfHI(p4) + w5 * bfHI(p5) + w6 * bfHI(p6) + w7 * bfHI(p7);
        den += w0 + w1 + w2 + w3 + w4 + w5 + w6 + w7;
    }
    if (e < e1) {   // masked 8-wide tail: one latency round instead of up to 7
        int iv = e + ew;
        bool inr = iv < e1;
        unsigned sv = col[inr ? iv : (e1 - 1)];
        int s0 = __builtin_amdgcn_readlane(sv, 0);
        int s1 = __builtin_amdgcn_readlane(sv, 1);
        int s2 = __builtin_amdgcn_readlane(sv, 2);
        int s3 = __builtin_amdgcn_readlane(sv, 3);
        int s4 = __builtin_amdgcn_readlane(sv, 4);
        int s5 = __builtin_amdgcn_readlane(sv, 5);
        int s6 = __builtin_amdgcn_readlane(sv, 6);
        int s7 = __builtin_amdgcn_readlane(sv, 7);
        unsigned p0 = hv[(size_t)s0 * 64 + lane];
        unsigned p1 = hv[(size_t)s1 * 64 + lane];
        unsigned p2 = hv[(size_t)s2 * 64 + lane];
        unsigned p3 = hv[(size_t)s3 * 64 + lane];
        unsigned p4 = hv[(size_t)s4 * 64 + lane];
        unsigned p5 = hv[(size_t)s5 * 64 + lane];
        unsigned p6 = hv[(size_t)s6 * 64 + lane];
        unsigned p7 = hv[(size_t)s7 * 64 + lane];
        float avv  = als1[(size_t)sv * 4 + hw];
        float wAll = inr ? __expf(lrelu(avv + advB)) : 0.f;
        float w0 = __shfl(wAll, bidx + 0);
        float w1 = __shfl(wAll, bidx + 1);
        float w2 = __shfl(wAll, bidx + 2);
        float w3 = __shfl(wAll, bidx + 3);
        float w4 = __shfl(wAll, bidx + 4);
        float w5 = __shfl(wAll, bidx + 5);
        float w6 = __shfl(wAll, bidx + 6);
        float w7 = __shfl(wAll, bidx + 7);
        a0 += w0 * bfLO(p0) + w1 * bfLO(p1) + w2 * bfLO(p2) + w3 * bfLO(p3);
        a0 += w4 * bfLO(p4) + w5 * bfLO(p5) + w6 * bfLO(p6) + w7 * bfLO(p7);
        a1 += w0 * bfHI(p0) + w1 * bfHI(p1) + w2 * bfHI(p2) + w3 * bfHI(p3);
        a1 += w4 * bfHI(p4) + w5 * bfHI(p5) + w6 * bfHI(p6) + w7 * bfHI(p7);
        den += w0 + w1 + w2 + w3 + w4 + w5 + w6 + w7;
    }
    float inv = 1.f / den;
    float2 bb = ((const float2*)b1)[lane];
    float2 o;
    o.x = elu(a0 * inv + bb.x);
    o.y = elu(a1 * inv + bb.y);
    ((float2*)h1)[(size_t)d * 64 + lane] = o;
}

// ---- dense2_k: h2 = h1 @ W2 (bf16 store) + layer-2 logits ----
__global__ __launch_bounds__(256) void dense2_k(
    const float* __restrict__ h1, const float* __restrict__ W2,
    const float* __restrict__ a_src2, const float* __restrict__ a_dst2,
    unsigned short* __restrict__ h2h, float* __restrict__ al_s2, float* __restrict__ al_d2)
{
    __shared__ float hs[32 * 132];    // rows stride 132 (==4 mod 32 -> 8 banks, bcast)
    __shared__ float W2s[128 * 32];   // flat: o-quads cover all 32 banks once
    __shared__ float h2s[32 * 36];
    int t = threadIdx.x;
    int n0 = blockIdx.x * 32;
#pragma unroll
    for (int j = 0; j < 4; ++j) {
        int q = t + 256 * j;                 // float4 id over 32x128
        int n = q >> 5, c0 = (q & 31) * 4;
        *(float4*)&hs[n * 132 + c0] = ((const float4*)h1)[(size_t)n0 * 32 + q];
        ((float4*)W2s)[q] = ((const float4*)W2)[q];
    }
    __syncthreads();
    int n = t >> 3, o4 = (t & 7) * 4;
    float4 acc = make_float4(0.f, 0.f, 0.f, 0.f);
#pragma unroll 8
    for (int k = 0; k < F_MID; ++k) {
        float a = hs[n * 132 + k];
        float4 w = *(const float4*)&W2s[k * 32 + o4];
        acc.x += a * w.x; acc.y += a * w.y; acc.z += a * w.z; acc.w += a * w.w;
    }
    unsigned lo = ((unsigned)f2bf(acc.y) << 16) | (unsigned)f2bf(acc.x);
    unsigned hi = ((unsigned)f2bf(acc.w) << 16) | (unsigned)f2bf(acc.z);
    ((uint2*)h2h)[(((size_t)(n0 + n)) * C2 + o4) >> 2] = make_uint2(lo, hi);
    *(float4*)&h2s[n * 36 + o4] = acc;
    __syncthreads();
    if (t < 64) {
        int which = t >> 5, nn = t & 31;
        const float* a = which ? a_dst2 : a_src2;
        float s = 0.f;
#pragma unroll
        for (int k = 0; k < C2; ++k) s += h2s[nn * 36 + k] * a[k];
        if (which) al_d2[n0 + nn] = s;
        else       al_s2[n0 + nn] = s;
    }
}

// ---- layer-2 gather (bf16 rows, 64 B) + normalize + ELU + pooled reduce ----
// 8 threads per dst, 32 dsts/block (r4-proven form; wave-per-dst regressed).
__global__ __launch_bounds__(256) void gather2(
    const int* __restrict__ row_ptr, const int* __restrict__ row_end,
    const unsigned* __restrict__ col, const float* __restrict__ al_src,
    const float* __restrict__ al_dst, const unsigned short* __restrict__ h2h,
    const float* __restrict__ b2, const int* __restrict__ batch,
    float* __restrict__ pooled)
{
    __shared__ float sv[32][C2];
    int t = threadIdx.x;
    int r = t >> 3;
    int c = t & 7;
    int d = blockIdx.x * 32 + r;
    const uint2* h2v = (const uint2*)h2h;
    float ad = al_dst[d];
    float w = __expf(lrelu(al_src[d] + ad));
    float4 v = bf2f4(h2v[(size_t)d * 8 + c]);
    float ax = w * v.x, ay = w * v.y, az = w * v.z, aw = w * v.w;
    float den = w;
    int e0 = row_ptr[d], e1 = row_end[d];
    int e = e0;
    for (; e + 4 <= e1; e += 4) {
        int s0 = (int)col[e], s1 = (int)col[e + 1], s2 = (int)col[e + 2], s3 = (int)col[e + 3];
        uint2 p0 = h2v[(size_t)s0 * 8 + c];
        uint2 p1 = h2v[(size_t)s1 * 8 + c];
        uint2 p2 = h2v[(size_t)s2 * 8 + c];
        uint2 p3 = h2v[(size_t)s3 * 8 + c];
        float4 v0 = bf2f4(p0);
        float4 v1 = bf2f4(p1);
        float4 v2 = bf2f4(p2);
        float4 v3 = bf2f4(p3);
        float w0 = __expf(lrelu(al_src[s0] + ad));
        float w1 = __expf(lrelu(al_src[s1] + ad));
        float w2 = __expf(lrelu(al_src[s2] + ad));
        float w3 = __expf(lrelu(al_src[s3] + ad));
        ax += w0 * v0.x + w1 * v1.x + w2 * v2.x + w3 * v3.x;
        ay += w0 * v0.y + w1 * v1.y + w2 * v2.y + w3 * v3.y;
        az += w0 * v0.z + w1 * v1.z + w2 * v2.z + w3 * v3.z;
        aw += w0 * v0.w + w1 * v1.w + w2 * v2.w + w3 * v3.w;
        den += w0 + w1 + w2 + w3;
    }
    if (e < e1) {   // masked 4-wide tail
        int last = e1 - 1;
        int i1 = (e + 1 < e1) ? e + 1 : last;
        int i2 = (e + 2 < e1) ? e + 2 : last;
        int s0 = (int)col[e], s1 = (int)col[i1], s2 = (int)col[i2];
        uint2 p0 = h2v[(size_t)s0 * 8 + c];
        uint2 p1 = h2v[(size_t)s1 * 8 + c];
        uint2 p2 = h2v[(size_t)s2 * 8 + c];
        float4 v0 = bf2f4(p0);
        float4 v1 = bf2f4(p1);
        float4 v2 = bf2f4(p2);
        float w0 = __expf(lrelu(al_src[s0] + ad));
        float w1 = (e + 1 < e1) ? __expf(lrelu(al_src[s1] + ad)) : 0.f;
        float w2 = (e + 2 < e1) ? __expf(lrelu(al_src[s2] + ad)) : 0.f;
        ax += w0 * v0.x + w1 * v1.x + w2 * v2.x;
        ay += w0 * v0.y + w1 * v1.y + w2 * v2.y;
        az += w0 * v0.z + w1 * v1.z + w2 * v2.z;
        aw += w0 * v0.w + w1 * v1.w + w2 * v2.w;
        den += w0 + w1 + w2;
    }
    float inv = 1.f / den;
    const float4 bv = ((const float4*)b2)[c];
    sv[r][4 * c + 0] = elu(ax * inv + bv.x);
    sv[r][4 * c + 1] = elu(ay * inv + bv.y);
    sv[r][4 * c + 2] = elu(az * inv + bv.z);
    sv[r][4 * c + 3] = elu(aw * inv + bv.w);
    __syncthreads();
    int d0 = blockIdx.x * 32;
    int g0 = batch[d0], g1 = batch[d0 + 31];
    if (t < 64) {
        int which = t >> 5, ch = t & 31;
        int g = which ? g1 : g0;
        if (which == 0 || g1 != g0) {
            float s = 0.f;
            for (int rr = 0; rr < 32; ++rr)
                if (batch[d0 + rr] == g) s += sv[rr][ch];
            atomicAdd(&pooled[g * C2 + ch], s);
        }
    }
}

// ---- classifier head: one thread per graph (400 nodes/graph exactly) ----
__global__ __launch_bounds__(256) void head_k(
    const float* __restrict__ pooled, const float* __restrict__ clinical,
    const float* __restrict__ Wc1, const float* __restrict__ bc1,
    const float* __restrict__ Wc2, const float* __restrict__ bc2,
    float* __restrict__ out)
{
    int g = threadIdx.x;
    float fused[C2 + CLIN];
    const float inv = 1.f / 400.f;
#pragma unroll
    for (int c = 0; c < C2; ++c) fused[c] = pooled[g * C2 + c] * inv;
#pragma unroll
    for (int c = 0; c < CLIN; ++c) fused[C2 + c] = clinical[g * CLIN + c];
    float o = bc2[0];
#pragma unroll
    for (int j = 0; j < 16; ++j) {
        float acc = bc1[j];
#pragma unroll
        for (int k = 0; k < C2 + CLIN; ++k) acc += fused[k] * Wc1[k * 16 + j];
        o += (acc > 0.f ? acc : expm1f(acc)) * Wc2[j];
    }
    out[g] = o;
}

extern "C" void kernel_launch(void* const* d_in, const int* in_sizes, int n_in,
                              void* d_out, int out_size, void* d_ws, size_t ws_size,
                              hipStream_t stream) {
    const float* x        = (const float*)d_in[0];
    const int*   ei       = (const int*)  d_in[1];
    const int*   batch    = (const int*)  d_in[2];
    const float* clinical = (const float*)d_in[3];
    const float* W1       = (const float*)d_in[4];
    const float* a_src1   = (const float*)d_in[5];
    const float* a_dst1   = (const float*)d_in[6];
    const float* b1       = (const float*)d_in[7];
    const float* W2       = (const float*)d_in[8];
    const float* a_src2   = (const float*)d_in[9];
    const float* a_dst2   = (const float*)d_in[10];
    const float* b2       = (const float*)d_in[11];
    const float* Wc1      = (const float*)d_in[12];
    const float* bc1      = (const float*)d_in[13];
    const float* Wc2      = (const float*)d_in[14];
    const float* bc2      = (const float*)d_in[15];
    float* out = (float*)d_out;

    const size_t N = N_NODES;
    float* ws = (float*)d_ws;
    size_t off = 0;
    float* als1   = ws + off; off += N * 4;
    float* ald1   = ws + off; off += N * 4;
    float* al_s2  = ws + off; off += N;
    float* al_d2  = ws + off; off += N;
    float* pooled = ws + off; off += (size_t)G_GRAPHS * C2;
    unsigned short* hth = (unsigned short*)(ws + off); off += N * F_MID / 2;  // bf16 h~
    float* h1     = ws + off; off += N * F_MID;                               // fp32 h1
    unsigned short* h2h = (unsigned short*)(ws + off); off += N * C2 / 2;     // bf16 h2
    int* row_ptr = (int*)(ws + off); off += N;
    int* row_end = (int*)(ws + off); off += N;
    int* gcnt    = (int*)(ws + off); off += 256;
    unsigned* binned = (unsigned*)(ws + off); off += (size_t)G_GRAPHS * CAPB; // also final col

    hipMemsetAsync(gcnt, 0, 256 * sizeof(int), stream);
    hipMemsetAsync(pooled, 0, G_GRAPHS * C2 * sizeof(float), stream);

    // CSR build: LDS binning
    bin_k  <<<N_EDGES / 4096, 256, 0, stream>>>(ei, gcnt, binned);
    build_k<<<G_GRAPHS, 512, 0, stream>>>(gcnt, binned, row_ptr, row_end);

    // h~ = x@W1 (bf16 table) + layer-1 logits (split src/dst)
    ht_k<<<N_NODES / 32, 256, 0, stream>>>(x, W1, a_src1, a_dst1, hth, als1, ald1);

    // barrier-free layer-1 aggregation -> h1 fp32
    agg1_k<<<N_NODES / 4, 256, 0, stream>>>(row_ptr, row_end, binned, hth, als1, ald1,
                                            b1, h1);

    // h2 = h1@W2 (bf16) + layer-2 logits
    dense2_k<<<N_NODES / 32, 256, 0, stream>>>(h1, W2, a_src2, a_dst2, h2h, al_s2, al_d2);

    // layer 2 gather (8 threads/dst) + fused pooling
    gather2<<<N_NODES / 32, 256, 0, stream>>>(row_ptr, row_end, binned, al_s2, al_d2, h2h,
                                              b2, batch, pooled);

    // head
    head_k<<<1, G_GRAPHS, 0, stream>>>(pooled, clinical, Wc1, bc1, Wc2, bc2, out);
}